// Round 15
// baseline (178.719 us; speedup 1.0000x reference)
//
#include <hip/hip_runtime.h>
#include <hip/hip_bf16.h>
#include <math.h>

#define NB 8
#define HH 64
#define WW 64
#define C 192
#define G 12
#define GC 16
#define P 9
#define NPIX (NB*HH*WW)

typedef __attribute__((ext_vector_type(8))) short short8;
typedef __attribute__((ext_vector_type(4))) float f32x4;
typedef unsigned short ushort;

__device__ __forceinline__ ushort to_bf16(float f) {
  __hip_bfloat16 b = __float2bfloat16(f);
  return *(ushort*)&b;
}
__device__ __forceinline__ float bf2f(ushort u) {
  union { unsigned u; float f; } cv; cv.u = ((unsigned)u) << 16; return cv.f;
}
__device__ __forceinline__ float bflo(unsigned u) {
  union { unsigned v; float f; } c; c.v = u << 16; return c.f;
}
__device__ __forceinline__ float bfhi(unsigned u) {
  union { unsigned v; float f; } c; c.v = u & 0xffff0000u; return c.f;
}

// ---------------- weight prep: transpose to [n][k] bf16 + fused bias ----------------
__global__ void prep_w_kernel(const float* __restrict__ in_w, const float* __restrict__ out_w,
    const float* __restrict__ off_w, const float* __restrict__ msk_w, const float* __restrict__ cfs_w,
    const float* __restrict__ off_b, const float* __restrict__ msk_b, const float* __restrict__ cfs_b,
    ushort* __restrict__ in_wt, ushort* __restrict__ out_wt, ushort* __restrict__ wf_t,
    float* __restrict__ bf_bias) {
  int idx = blockIdx.x*256 + threadIdx.x;
  if (idx < 36864) {
    int n = idx/192, k = idx%192;
    in_wt[idx] = to_bf16(in_w[k*192 + n]);
  } else if (idx < 73728) {
    int j = idx - 36864; int n = j/192, k = j%192;
    out_wt[j] = to_bf16(out_w[k*192 + n]);
  } else if (idx < 147456) {
    int j = idx - 73728; int n = j/192, k = j%192;
    float v = 0.f;
    if (n < 216)      v = off_w[k*216 + n];
    else if (n < 324) v = msk_w[k*108 + (n-216)];
    else if (n < 336) v = cfs_w[k*12  + (n-324)];
    wf_t[j] = to_bf16(v);
  }
  if (idx < 384) {
    float b = 0.f;
    if (idx < 216)      b = off_b[idx];
    else if (idx < 324) b = msk_b[idx-216];
    else if (idx < 336) b = cfs_b[idx-324];
    bf_bias[idx] = b;
  }
}

// ------- bf16 MFMA GEMM, 64x64 tile (4 waves x 32x32) -------
template<int NW, int NSTORE, bool BF16OUT, bool AF32>
__global__ __launch_bounds__(256) void mfma_gemm(const void* __restrict__ A_,
    const ushort* __restrict__ Wt, const float* __restrict__ bias,
    void* __restrict__ Cout_) {
  __shared__ ushort As[4*64*8];   // 4KB
  __shared__ ushort Bs[4*64*8];   // 4KB
  int pix0 = blockIdx.x * 64, n0 = blockIdx.y * 64;
  int tid = threadIdx.x;
  int wid = tid >> 6, lane = tid & 63;
  int wr = wid >> 1, wc = wid & 1;
  int lr = lane >> 4, lc = lane & 15;

  f32x4 acc[2][2];
  #pragma unroll
  for (int m=0;m<2;m++)
    #pragma unroll
    for (int j=0;j<2;j++) acc[m][j] = (f32x4){0.f,0.f,0.f,0.f};

  int s_kb = tid >> 6, s_row = tid & 63;

  short8 pa, pb;
  auto load_tile = [&](int k0) {
    if (AF32) {
      const float* Af = (const float*)A_;
      float4 u0 = *(const float4*)&Af[(size_t)(pix0 + s_row)*192 + k0 + s_kb*8];
      float4 u1 = *(const float4*)&Af[(size_t)(pix0 + s_row)*192 + k0 + s_kb*8 + 4];
      pa[0]=to_bf16(u0.x); pa[1]=to_bf16(u0.y); pa[2]=to_bf16(u0.z); pa[3]=to_bf16(u0.w);
      pa[4]=to_bf16(u1.x); pa[5]=to_bf16(u1.y); pa[6]=to_bf16(u1.z); pa[7]=to_bf16(u1.w);
    } else {
      const ushort* Ab = (const ushort*)A_;
      pa = *(const short8*)&Ab[(size_t)(pix0 + s_row)*192 + k0 + s_kb*8];
    }
    pb = *(const short8*)&Wt[(size_t)(n0 + s_row)*192 + k0 + s_kb*8];
  };
  load_tile(0);

  for (int t = 0; t < 6; t++) {
    __syncthreads();
    *(short8*)&As[(size_t)tid*8] = pa;
    *(short8*)&Bs[(size_t)tid*8] = pb;
    __syncthreads();
    if (t < 5) load_tile((t+1)*32);
    short8 a0 = *(const short8*)&As[(size_t)(lr*64 + wr*32 + lc)*8];
    short8 a1 = *(const short8*)&As[(size_t)(lr*64 + wr*32 + 16 + lc)*8];
    short8 b0 = *(const short8*)&Bs[(size_t)(lr*64 + wc*32 + lc)*8];
    short8 b1 = *(const short8*)&Bs[(size_t)(lr*64 + wc*32 + 16 + lc)*8];
    acc[0][0] = __builtin_amdgcn_mfma_f32_16x16x32_bf16(a0, b0, acc[0][0], 0,0,0);
    acc[0][1] = __builtin_amdgcn_mfma_f32_16x16x32_bf16(a0, b1, acc[0][1], 0,0,0);
    acc[1][0] = __builtin_amdgcn_mfma_f32_16x16x32_bf16(a1, b0, acc[1][0], 0,0,0);
    acc[1][1] = __builtin_amdgcn_mfma_f32_16x16x32_bf16(a1, b1, acc[1][1], 0,0,0);
  }
  #pragma unroll
  for (int j=0;j<2;j++) {
    int col = n0 + wc*32 + j*16 + lc;
    if (NW != NSTORE && col >= NSTORE) continue;
    float bb = bias[col];
    #pragma unroll
    for (int m=0;m<2;m++) {
      size_t rbase = pix0 + wr*32 + m*16 + lr*4;
      #pragma unroll
      for (int r=0;r<4;r++) {
        float v = acc[m][j][r] + bb;
        if (BF16OUT) ((ushort*)Cout_)[(rbase + r)*NSTORE + col] = to_bf16(v);
        else         ((float*) Cout_)[(rbase + r)*NSTORE + col] = v;
      }
    }
  }
}

// ------- depthwise 5x5 + LN + GELU, sliding-window, XCD-swizzled blocks -------
#define SEG 16
__global__ __launch_bounds__(192) void dw_ln_gelu_kernel(const float* __restrict__ x,
    const float* __restrict__ dw_w, const float* __restrict__ dw_b,
    const float* __restrict__ ln_g, const float* __restrict__ ln_b,
    ushort* __restrict__ u_out) {
  int bid = blockIdx.x;
  int blk = (bid & 7) * 256 + (bid >> 3);
  int qw = blk & 3; int nh = blk >> 2;
  int h = nh & 63, n = nh >> 6;
  int c = threadIdx.x;
  int w0 = qw * SEG;

  float kw[25];
  #pragma unroll
  for (int t=0;t<25;t++) kw[t] = dw_w[t*C + c];

  float acc[SEG];
  float bb = dw_b[c];
  #pragma unroll
  for (int i=0;i<SEG;i++) acc[i] = bb;

  #pragma unroll
  for (int i=0;i<5;i++) {
    int hy = h + i - 2;
    if (hy < 0 || hy >= HH) continue;
    const float* rowp = &x[(((size_t)n*HH + hy)*WW)*C + c];
    #pragma unroll
    for (int wi=0; wi<SEG+4; wi++) {
      int w_in = w0 - 2 + wi;
      if (w_in < 0 || w_in >= WW) continue;
      float v = rowp[(size_t)w_in*C];
      #pragma unroll
      for (int j=0;j<5;j++) {
        int a = wi - j;
        if (a >= 0 && a < SEG) acc[a] += v * kw[i*5+j];
      }
    }
  }

  __shared__ float lds_acc[SEG][C+1];
  __shared__ float part1[SEG][12], part2[SEG][12];
  __shared__ float mu_s[SEG], rs_s[SEG];
  #pragma unroll
  for (int i=0;i<SEG;i++) lds_acc[i][c] = acc[i];
  __syncthreads();
  {
    int p = threadIdx.x & 15, chunk = threadIdx.x >> 4;
    float s1 = 0.f, s2 = 0.f;
    #pragma unroll
    for (int k=0;k<16;k++) {
      float v = lds_acc[p][chunk*16 + k];
      s1 += v; s2 += v*v;
    }
    part1[p][chunk] = s1; part2[p][chunk] = s2;
  }
  __syncthreads();
  if (threadIdx.x < SEG) {
    int p = threadIdx.x;
    float t1 = 0.f, t2 = 0.f;
    #pragma unroll
    for (int k=0;k<12;k++){ t1 += part1[p][k]; t2 += part2[p][k]; }
    float mu = t1 * (1.0f/C);
    float var = t2 * (1.0f/C) - mu*mu;
    mu_s[p] = mu; rs_s[p] = rsqrtf(var + 1e-5f);
  }
  __syncthreads();
  float gg = ln_g[c], lb = ln_b[c];
  size_t obase = ((size_t)nh*WW + w0)*C + c;
  #pragma unroll
  for (int i=0;i<SEG;i++) {
    float uv = (acc[i] - mu_s[i])*rs_s[i]*gg + lb;
    uv = 0.5f*uv*(1.0f + erff(uv*0.70710678118654752f));
    u_out[obase + (size_t)i*C] = to_bf16(uv);
  }
}

// ------- samgemm: fused DCNv3 sample + gated blend + out-projection GEMM ----------
// block = 64 px (one image row). Phases: A softmax->LDS, B gather->y2 LDS (bf16,
// stride 200 ch), C MFMA x1 = y2 @ out_wt^T + out_b (A-frags from LDS, B from L2).
#define Y2STR 200
__device__ __forceinline__ void fma8(float* acc, float w, uint4 q) {
  acc[0] += w*bflo(q.x); acc[1] += w*bfhi(q.x);
  acc[2] += w*bflo(q.y); acc[3] += w*bfhi(q.y);
  acc[4] += w*bflo(q.z); acc[5] += w*bfhi(q.z);
  acc[6] += w*bflo(q.w); acc[7] += w*bfhi(q.w);
}
__global__ __launch_bounds__(256) void samgemm_kernel(const ushort* __restrict__ omc,
    const ushort* __restrict__ x_proj, const ushort* __restrict__ out_wt,
    const float* __restrict__ out_b, ushort* __restrict__ x1_out) {
  __shared__ ushort y2lds[64*Y2STR];     // 25600 B
  __shared__ ushort msm_lds[64*108];     // 13824 B (premultiplied (1-cf)*softmax, bf16)
  __shared__ float  cfs_lds[64*12];      // 3072 B
  // XCD swizzle: 512 blocks, 64 per XCD = one image per XCD
  int bid = blockIdx.x;
  int blk = (bid & 7) * 64 + (bid >> 3);
  int pix0 = blk * 64;
  int n = pix0 >> 12; int h = (pix0 & 4095) >> 6;   // w0 = 0, row-aligned
  int tid = threadIdx.x;

  // Phase A: softmax + sigmoid, premultiplied mask -> LDS (64*12 = 768 tasks)
  #pragma unroll
  for (int k = 0; k < 3; k++) {
    int task = tid + k*256;
    int pxl = task / 12, g = task % 12;
    size_t pix = pix0 + pxl;
    const ushort* mrow = &omc[pix*336 + 216 + g*9];
    float lv[P];
    #pragma unroll
    for (int p=0;p<P;p++) lv[p] = bf2f(mrow[p]);
    float m = lv[0];
    #pragma unroll
    for (int p=1;p<P;p++) m = fmaxf(m, lv[p]);
    float s = 0.f;
    #pragma unroll
    for (int p=0;p<P;p++){ lv[p] = expf(lv[p]-m); s += lv[p]; }
    float cf = 1.0f/(1.0f+expf(-bf2f(omc[pix*336 + 324 + g])));
    cfs_lds[task] = cf;
    float onem = (1.0f - cf) / s;
    #pragma unroll
    for (int p=0;p<P;p++)
      msm_lds[pxl*108 + g*9 + p] = to_bf16(lv[p]*onem);
  }
  __syncthreads();

  // Phase B: gather -> y2 LDS (64*24 = 1536 slice-tasks, 6 per thread)
  {
    const char* xb = (const char*)x_proj;
    const unsigned* omc32 = (const unsigned*)omc;
    int base = n*HH*WW*C;
    const float pts[3] = {-1.f, 0.f, 1.f};
    #pragma unroll
    for (int k = 0; k < 6; k++) {
      int task = tid + k*256;
      int pxl = task / 24, s = task - (task/24)*24;
      int g = s >> 1;
      int w = pxl;                       // w == pxl since block is one row
      size_t pix = pix0 + pxl;
      int cb = s * 16;
      float acc[8] = {0.f,0.f,0.f,0.f,0.f,0.f,0.f,0.f};
      #pragma unroll
      for (int pb = 0; pb < 3; pb++) {
        int a_[12]; float w_[12];
        #pragma unroll
        for (int j3 = 0; j3 < 3; j3++) {
          int p = pb*3 + j3;
          unsigned off2 = omc32[pix*168 + g*9 + p];
          float ox = bflo(off2), oy = bfhi(off2);
          float gx = 1.0f + (float)w + pts[p/3] + ox;
          float gy = 1.0f + (float)h + pts[p%3] + oy;
          float x0f = floorf(gx), y0f = floorf(gy);
          float wx1 = gx-x0f, wy1 = gy-y0f;
          float wx0 = 1.f-wx1, wy0 = 1.f-wy1;
          int x0 = (int)x0f, y0 = (int)y0f;
          bool xv0 = (x0>=1)&&(x0<=64), xv1 = (x0>=0)&&(x0<=63);
          bool yv0 = (y0>=1)&&(y0<=64), yv1 = (y0>=0)&&(y0<=63);
          float m = bf2f(msm_lds[pxl*108 + g*9 + p]);
          a_[j3*4+0] = (yv0&&xv0) ? (base + ((y0-1)*WW + (x0-1))*C)*2 : 0;
          a_[j3*4+1] = (yv0&&xv1) ? (base + ((y0-1)*WW + (x0  ))*C)*2 : 0;
          a_[j3*4+2] = (yv1&&xv0) ? (base + ((y0  )*WW + (x0-1))*C)*2 : 0;
          a_[j3*4+3] = (yv1&&xv1) ? (base + ((y0  )*WW + (x0  ))*C)*2 : 0;
          w_[j3*4+0] = (yv0&&xv0) ? wx0*wy0*m : 0.f;
          w_[j3*4+1] = (yv0&&xv1) ? wx1*wy0*m : 0.f;
          w_[j3*4+2] = (yv1&&xv0) ? wx0*wy1*m : 0.f;
          w_[j3*4+3] = (yv1&&xv1) ? wx1*wy1*m : 0.f;
        }
        uint4 t0 = *(const uint4*)(xb + (unsigned)(a_[0] + cb));
        uint4 t1 = *(const uint4*)(xb + (unsigned)(a_[1] + cb));
        uint4 t2 = *(const uint4*)(xb + (unsigned)(a_[2] + cb));
        uint4 t3 = *(const uint4*)(xb + (unsigned)(a_[3] + cb));
        uint4 t4 = *(const uint4*)(xb + (unsigned)(a_[4] + cb));
        uint4 t5 = *(const uint4*)(xb + (unsigned)(a_[5] + cb));
        uint4 t6 = *(const uint4*)(xb + (unsigned)(a_[6] + cb));
        uint4 t7 = *(const uint4*)(xb + (unsigned)(a_[7] + cb));
        uint4 t8 = *(const uint4*)(xb + (unsigned)(a_[8] + cb));
        uint4 t9 = *(const uint4*)(xb + (unsigned)(a_[9] + cb));
        uint4 ta = *(const uint4*)(xb + (unsigned)(a_[10] + cb));
        uint4 tb = *(const uint4*)(xb + (unsigned)(a_[11] + cb));
        fma8(acc, w_[0], t0); fma8(acc, w_[1], t1);
        fma8(acc, w_[2], t2); fma8(acc, w_[3], t3);
        fma8(acc, w_[4], t4); fma8(acc, w_[5], t5);
        fma8(acc, w_[6], t6); fma8(acc, w_[7], t7);
        fma8(acc, w_[8], t8); fma8(acc, w_[9], t9);
        fma8(acc, w_[10], ta); fma8(acc, w_[11], tb);
      }
      float cf = cfs_lds[pxl*12 + g];
      uint4 qx = *(const uint4*)(xb + pix*384 + cb);
      fma8(acc, cf, qx);
      short8 r;
      #pragma unroll
      for (int q=0;q<8;q++) r[q] = to_bf16(acc[q]);
      *(short8*)&y2lds[pxl*Y2STR + s*8] = r;
    }
  }
  __syncthreads();

  // Phase C: x1[64][192] = y2 @ out_wt^T + out_b (A from LDS, B from global/L2)
  {
    int wid = tid >> 6, lane = tid & 63;
    int wr = wid >> 1, wc = wid & 1;
    int lr = lane >> 4, lc = lane & 15;
    #pragma unroll
    for (int n0t = 0; n0t < 3; n0t++) {
      int n0 = n0t * 64;
      f32x4 acc[2][2];
      #pragma unroll
      for (int m=0;m<2;m++)
        #pragma unroll
        for (int j=0;j<2;j++) acc[m][j] = (f32x4){0.f,0.f,0.f,0.f};
      #pragma unroll
      for (int t = 0; t < 6; t++) {
        short8 a0 = *(const short8*)&y2lds[(wr*32 + lc)*Y2STR + t*32 + lr*8];
        short8 a1 = *(const short8*)&y2lds[(wr*32 + 16 + lc)*Y2STR + t*32 + lr*8];
        short8 b0 = *(const short8*)&out_wt[(size_t)(n0 + wc*32 + lc)*192 + t*32 + lr*8];
        short8 b1 = *(const short8*)&out_wt[(size_t)(n0 + wc*32 + 16 + lc)*192 + t*32 + lr*8];
        acc[0][0] = __builtin_amdgcn_mfma_f32_16x16x32_bf16(a0, b0, acc[0][0], 0,0,0);
        acc[0][1] = __builtin_amdgcn_mfma_f32_16x16x32_bf16(a0, b1, acc[0][1], 0,0,0);
        acc[1][0] = __builtin_amdgcn_mfma_f32_16x16x32_bf16(a1, b0, acc[1][0], 0,0,0);
        acc[1][1] = __builtin_amdgcn_mfma_f32_16x16x32_bf16(a1, b1, acc[1][1], 0,0,0);
      }
      #pragma unroll
      for (int j=0;j<2;j++) {
        int col = n0 + wc*32 + j*16 + lc;
        float bb = out_b[col];
        #pragma unroll
        for (int m=0;m<2;m++) {
          size_t rbase = pix0 + wr*32 + m*16 + lr*4;
          #pragma unroll
          for (int r=0;r<4;r++)
            x1_out[(rbase + r)*192 + col] = to_bf16(acc[m][j][r] + bb);
        }
      }
    }
  }
}

// ---------------- patch attention, LDS-tiled 8x8 px/block ----------------
__global__ __launch_bounds__(256) void pattn_kernel(const float* __restrict__ x,
    const ushort* __restrict__ x1, float* __restrict__ out) {
  __shared__ unsigned xs[100*97];      // 38800 B
  __shared__ float psc[64][36];        // 9216 B
  __shared__ float sd_s[64];
  int blk = blockIdx.x;
  int n = blk >> 6;
  int ty = (blk >> 3) & 7, tx = blk & 7;
  int th0 = ty*8, tw0 = tx*8;
  int tid = threadIdx.x;
  const unsigned* x1u = (const unsigned*)x1;
  for (int i = tid; i < 100*96; i += 256) {
    int cell = i / 96, wd = i - cell*96;
    int gy = th0 - 1 + cell/10, gx = tw0 - 1 + cell%10;
    unsigned v = 0;
    if (gy>=0 && gy<HH && gx>=0 && gx<WW)
      v = x1u[(((size_t)n*HH+gy)*WW+gx)*96 + wd];
    xs[cell*97 + wd] = v;
  }
  __syncthreads();
  {
    int px = tid >> 2, qq = tid & 3;
    int py = px >> 3, pxx = px & 7;
    int cell = (py+1)*10 + (pxx+1);
    float cen[48];
    #pragma unroll
    for (int k=0;k<24;k++) {
      unsigned w = xs[cell*97 + qq*24 + k];
      cen[2*k] = bflo(w); cen[2*k+1] = bfhi(w);
    }
    #pragma unroll
    for (int ni=0;ni<9;ni++) {
      int nc = cell + (ni/3-1)*10 + (ni%3-1);
      float a = 0.f;
      #pragma unroll
      for (int k=0;k<24;k++) {
        unsigned w = xs[nc*97 + qq*24 + k];
        a += cen[2*k]*bflo(w) + cen[2*k+1]*bfhi(w);
      }
      psc[px][qq*9+ni] = a;
    }
  }
  __syncthreads();
  if (tid < 64) {
    float sc[9];
    #pragma unroll
    for (int k=0;k<9;k++)
      sc[k] = psc[tid][k] + psc[tid][9+k] + psc[tid][18+k] + psc[tid][27+k];
    float m = sc[0];
    #pragma unroll
    for (int k=1;k<9;k++) m = fmaxf(m, sc[k]);
    float pr[9]; float s = 0.f;
    #pragma unroll
    for (int k=0;k<9;k++){ pr[k] = expf(sc[k]-m); s += pr[k]; }
    float inv = 1.0f/s;
    float mean = 0.f;
    #pragma unroll
    for (int k=0;k<9;k++){ pr[k] *= inv; mean += pr[k]; }
    mean *= (1.0f/9.0f);
    float var = 0.f;
    #pragma unroll
    for (int k=0;k<9;k++){ float d = pr[k]-mean; var += d*d; }
    sd_s[tid] = sqrtf(var*(1.0f/8.0f));
  }
  __syncthreads();
  for (int i = tid; i < 64*96; i += 256) {
    int p2 = i / 96, wd = i - p2*96;
    int py2 = p2 >> 3, px2 = p2 & 7;
    unsigned v = xs[((py2+1)*10 + (px2+1))*97 + wd];
    size_t pix = ((size_t)n*HH + th0+py2)*WW + tw0+px2;
    float2 xv = ((const float2*)x)[pix*96 + wd];
    float sd = sd_s[p2];
    float2 o; o.x = xv.x + bflo(v)*sd; o.y = xv.y + bfhi(v)*sd;
    ((float2*)out)[pix*96 + wd] = o;
  }
}

extern "C" void kernel_launch(void* const* d_in, const int* in_sizes, int n_in,
                              void* d_out, int out_size, void* d_ws, size_t ws_size,
                              hipStream_t stream) {
  const float* x     = (const float*)d_in[0];
  const float* dw_w  = (const float*)d_in[1];
  const float* dw_b  = (const float*)d_in[2];
  const float* ln_g  = (const float*)d_in[3];
  const float* ln_b  = (const float*)d_in[4];
  const float* off_w = (const float*)d_in[5];
  const float* off_b = (const float*)d_in[6];
  const float* msk_w = (const float*)d_in[7];
  const float* msk_b = (const float*)d_in[8];
  const float* in_w  = (const float*)d_in[9];
  const float* in_b  = (const float*)d_in[10];
  const float* out_w = (const float*)d_in[11];
  const float* out_b = (const float*)d_in[12];
  const float* cfs_w = (const float*)d_in[13];
  const float* cfs_b = (const float*)d_in[14];
  float* outp = (float*)d_out;

  ushort* omc     = (ushort*)d_ws;                        // NPIX*336 bf16
  ushort* xproj   = omc + (size_t)NPIX*336;               // NPIX*192 bf16
  ushort* x1_bf   = xproj + (size_t)NPIX*192;             // NPIX*192 bf16
  ushort* u_bf    = x1_bf + (size_t)NPIX*192;             // NPIX*192 bf16
  ushort* in_wt   = u_bf + (size_t)NPIX*192;              // 192*192
  ushort* out_wt  = in_wt + 192*192;                      // 192*192
  ushort* wf_t    = out_wt + 192*192;                     // 384*192
  float*  bfb     = (float*)(wf_t + 384*192);             // 384 f32

  prep_w_kernel<<<(147456+255)/256, 256, 0, stream>>>(in_w, out_w, off_w, msk_w, cfs_w,
                                                       off_b, msk_b, cfs_b,
                                                       in_wt, out_wt, wf_t, bfb);
  // x_proj (bf16) = x @ in_w + in_b
  mfma_gemm<192,192,true,true><<<dim3(NPIX/64, 3), 256, 0, stream>>>(x, in_wt, in_b, xproj);
  // u (bf16) = GELU(LN(dwconv(x)))
  dw_ln_gelu_kernel<<<NB*HH*4, 192, 0, stream>>>(x, dw_w, dw_b, ln_g, ln_b, u_bf);
  // omc (bf16) = u @ wf + bf
  mfma_gemm<384,336,true,false><<<dim3(NPIX/64, 6), 256, 0, stream>>>(u_bf, wf_t, bfb, omc);
  // x1 (bf16) = (dcn-sample + blend) @ out_w + out_b   [fused, y2 never hits HBM]
  samgemm_kernel<<<NPIX/64, 256, 0, stream>>>(omc, xproj, out_wt, out_b, x1_bf);
  // out = x + x1 * patch_std
  pattn_kernel<<<NB*64, 256, 0, stream>>>(x, x1_bf, outp);
}

// Round 16
// 149.838 us; speedup vs baseline: 1.1927x; 1.1927x over previous
//
#include <hip/hip_runtime.h>
#include <hip/hip_bf16.h>
#include <math.h>

#define NB 8
#define HH 64
#define WW 64
#define C 192
#define G 12
#define GC 16
#define P 9
#define NPIX (NB*HH*WW)

typedef __attribute__((ext_vector_type(8))) short short8;
typedef __attribute__((ext_vector_type(4))) float f32x4;
typedef unsigned short ushort;

__device__ __forceinline__ ushort to_bf16(float f) {
  __hip_bfloat16 b = __float2bfloat16(f);
  return *(ushort*)&b;
}
__device__ __forceinline__ float bf2f(ushort u) {
  union { unsigned u; float f; } cv; cv.u = ((unsigned)u) << 16; return cv.f;
}
__device__ __forceinline__ float bflo(unsigned u) {
  union { unsigned v; float f; } c; c.v = u << 16; return c.f;
}
__device__ __forceinline__ float bfhi(unsigned u) {
  union { unsigned v; float f; } c; c.v = u & 0xffff0000u; return c.f;
}

// ---------------- weight prep: transpose to [n][k] bf16 + fused bias ----------------
__global__ void prep_w_kernel(const float* __restrict__ in_w, const float* __restrict__ out_w,
    const float* __restrict__ off_w, const float* __restrict__ msk_w, const float* __restrict__ cfs_w,
    const float* __restrict__ off_b, const float* __restrict__ msk_b, const float* __restrict__ cfs_b,
    ushort* __restrict__ in_wt, ushort* __restrict__ out_wt, ushort* __restrict__ wf_t,
    float* __restrict__ bf_bias) {
  int idx = blockIdx.x*256 + threadIdx.x;
  if (idx < 36864) {
    int n = idx/192, k = idx%192;
    in_wt[idx] = to_bf16(in_w[k*192 + n]);
  } else if (idx < 73728) {
    int j = idx - 36864; int n = j/192, k = j%192;
    out_wt[j] = to_bf16(out_w[k*192 + n]);
  } else if (idx < 147456) {
    int j = idx - 73728; int n = j/192, k = j%192;
    float v = 0.f;
    if (n < 216)      v = off_w[k*216 + n];
    else if (n < 324) v = msk_w[k*108 + (n-216)];
    else if (n < 336) v = cfs_w[k*12  + (n-324)];
    wf_t[j] = to_bf16(v);
  }
  if (idx < 384) {
    float b = 0.f;
    if (idx < 216)      b = off_b[idx];
    else if (idx < 324) b = msk_b[idx-216];
    else if (idx < 336) b = cfs_b[idx-324];
    bf_bias[idx] = b;
  }
}

// ------- bf16 MFMA GEMM, 64x64 tile (4 waves x 32x32) -------
template<int NW, int NSTORE, bool BF16OUT, bool AF32>
__global__ __launch_bounds__(256) void mfma_gemm(const void* __restrict__ A_,
    const ushort* __restrict__ Wt, const float* __restrict__ bias,
    void* __restrict__ Cout_) {
  __shared__ ushort As[4*64*8];   // 4KB
  __shared__ ushort Bs[4*64*8];   // 4KB
  int pix0 = blockIdx.x * 64, n0 = blockIdx.y * 64;
  int tid = threadIdx.x;
  int wid = tid >> 6, lane = tid & 63;
  int wr = wid >> 1, wc = wid & 1;
  int lr = lane >> 4, lc = lane & 15;

  f32x4 acc[2][2];
  #pragma unroll
  for (int m=0;m<2;m++)
    #pragma unroll
    for (int j=0;j<2;j++) acc[m][j] = (f32x4){0.f,0.f,0.f,0.f};

  int s_kb = tid >> 6, s_row = tid & 63;

  short8 pa, pb;
  auto load_tile = [&](int k0) {
    if (AF32) {
      const float* Af = (const float*)A_;
      float4 u0 = *(const float4*)&Af[(size_t)(pix0 + s_row)*192 + k0 + s_kb*8];
      float4 u1 = *(const float4*)&Af[(size_t)(pix0 + s_row)*192 + k0 + s_kb*8 + 4];
      pa[0]=to_bf16(u0.x); pa[1]=to_bf16(u0.y); pa[2]=to_bf16(u0.z); pa[3]=to_bf16(u0.w);
      pa[4]=to_bf16(u1.x); pa[5]=to_bf16(u1.y); pa[6]=to_bf16(u1.z); pa[7]=to_bf16(u1.w);
    } else {
      const ushort* Ab = (const ushort*)A_;
      pa = *(const short8*)&Ab[(size_t)(pix0 + s_row)*192 + k0 + s_kb*8];
    }
    pb = *(const short8*)&Wt[(size_t)(n0 + s_row)*192 + k0 + s_kb*8];
  };
  load_tile(0);

  for (int t = 0; t < 6; t++) {
    __syncthreads();
    *(short8*)&As[(size_t)tid*8] = pa;
    *(short8*)&Bs[(size_t)tid*8] = pb;
    __syncthreads();
    if (t < 5) load_tile((t+1)*32);
    short8 a0 = *(const short8*)&As[(size_t)(lr*64 + wr*32 + lc)*8];
    short8 a1 = *(const short8*)&As[(size_t)(lr*64 + wr*32 + 16 + lc)*8];
    short8 b0 = *(const short8*)&Bs[(size_t)(lr*64 + wc*32 + lc)*8];
    short8 b1 = *(const short8*)&Bs[(size_t)(lr*64 + wc*32 + 16 + lc)*8];
    acc[0][0] = __builtin_amdgcn_mfma_f32_16x16x32_bf16(a0, b0, acc[0][0], 0,0,0);
    acc[0][1] = __builtin_amdgcn_mfma_f32_16x16x32_bf16(a0, b1, acc[0][1], 0,0,0);
    acc[1][0] = __builtin_amdgcn_mfma_f32_16x16x32_bf16(a1, b0, acc[1][0], 0,0,0);
    acc[1][1] = __builtin_amdgcn_mfma_f32_16x16x32_bf16(a1, b1, acc[1][1], 0,0,0);
  }
  #pragma unroll
  for (int j=0;j<2;j++) {
    int col = n0 + wc*32 + j*16 + lc;
    if (NW != NSTORE && col >= NSTORE) continue;
    float bb = bias[col];
    #pragma unroll
    for (int m=0;m<2;m++) {
      size_t rbase = pix0 + wr*32 + m*16 + lr*4;
      #pragma unroll
      for (int r=0;r<4;r++) {
        float v = acc[m][j][r] + bb;
        if (BF16OUT) ((ushort*)Cout_)[(rbase + r)*NSTORE + col] = to_bf16(v);
        else         ((float*) Cout_)[(rbase + r)*NSTORE + col] = v;
      }
    }
  }
}

// ------- depthwise 5x5 + LN + GELU, sliding-window, XCD-swizzled blocks -------
#define SEG 16
__global__ __launch_bounds__(192) void dw_ln_gelu_kernel(const float* __restrict__ x,
    const float* __restrict__ dw_w, const float* __restrict__ dw_b,
    const float* __restrict__ ln_g, const float* __restrict__ ln_b,
    ushort* __restrict__ u_out) {
  int bid = blockIdx.x;
  int blk = (bid & 7) * 256 + (bid >> 3);
  int qw = blk & 3; int nh = blk >> 2;
  int h = nh & 63, n = nh >> 6;
  int c = threadIdx.x;
  int w0 = qw * SEG;

  float kw[25];
  #pragma unroll
  for (int t=0;t<25;t++) kw[t] = dw_w[t*C + c];

  float acc[SEG];
  float bb = dw_b[c];
  #pragma unroll
  for (int i=0;i<SEG;i++) acc[i] = bb;

  #pragma unroll
  for (int i=0;i<5;i++) {
    int hy = h + i - 2;
    if (hy < 0 || hy >= HH) continue;
    const float* rowp = &x[(((size_t)n*HH + hy)*WW)*C + c];
    #pragma unroll
    for (int wi=0; wi<SEG+4; wi++) {
      int w_in = w0 - 2 + wi;
      if (w_in < 0 || w_in >= WW) continue;
      float v = rowp[(size_t)w_in*C];
      #pragma unroll
      for (int j=0;j<5;j++) {
        int a = wi - j;
        if (a >= 0 && a < SEG) acc[a] += v * kw[i*5+j];
      }
    }
  }

  __shared__ float lds_acc[SEG][C+1];
  __shared__ float part1[SEG][12], part2[SEG][12];
  __shared__ float mu_s[SEG], rs_s[SEG];
  #pragma unroll
  for (int i=0;i<SEG;i++) lds_acc[i][c] = acc[i];
  __syncthreads();
  {
    int p = threadIdx.x & 15, chunk = threadIdx.x >> 4;
    float s1 = 0.f, s2 = 0.f;
    #pragma unroll
    for (int k=0;k<16;k++) {
      float v = lds_acc[p][chunk*16 + k];
      s1 += v; s2 += v*v;
    }
    part1[p][chunk] = s1; part2[p][chunk] = s2;
  }
  __syncthreads();
  if (threadIdx.x < SEG) {
    int p = threadIdx.x;
    float t1 = 0.f, t2 = 0.f;
    #pragma unroll
    for (int k=0;k<12;k++){ t1 += part1[p][k]; t2 += part2[p][k]; }
    float mu = t1 * (1.0f/C);
    float var = t2 * (1.0f/C) - mu*mu;
    mu_s[p] = mu; rs_s[p] = rsqrtf(var + 1e-5f);
  }
  __syncthreads();
  float gg = ln_g[c], lb = ln_b[c];
  size_t obase = ((size_t)nh*WW + w0)*C + c;
  #pragma unroll
  for (int i=0;i<SEG;i++) {
    float uv = (acc[i] - mu_s[i])*rs_s[i]*gg + lb;
    uv = 0.5f*uv*(1.0f + erff(uv*0.70710678118654752f));
    u_out[obase + (size_t)i*C] = to_bf16(uv);
  }
}

// ---------------- DCNv3 sampling + gated blend, 8 px/block, bf16 wts, XCD swizzle -------
#define SPX 8
__device__ __forceinline__ void fma8(float* acc, float w, uint4 q) {
  acc[0] += w*bflo(q.x); acc[1] += w*bfhi(q.x);
  acc[2] += w*bflo(q.y); acc[3] += w*bfhi(q.y);
  acc[4] += w*bflo(q.z); acc[5] += w*bfhi(q.z);
  acc[6] += w*bflo(q.w); acc[7] += w*bfhi(q.w);
}
__global__ __launch_bounds__(192) void sample_kernel(const ushort* __restrict__ omc,
    const ushort* __restrict__ x_proj, ushort* __restrict__ y_out) {
  int bid = blockIdx.x;
  int swz = (bid & 7) * 512 + (bid >> 3);
  int pix0 = swz * SPX;
  int n = pix0 >> 12;
  int hw = pix0 & 4095; int h = hw >> 6; int w0 = hw & 63;
  int tid = threadIdx.x;
  __shared__ int    addrs[SPX*108*4];     // 13824 B
  __shared__ ushort wts16[SPX*108*4];     // 6912 B
  __shared__ float  cfss[SPX][12];        // 384 B

  for (int i = tid; i < SPX*108; i += 192) {
    int px = i / 108, gp = i % 108;
    int p = gp % 9;
    const float pts[3] = {-1.f, 0.f, 1.f};
    unsigned off2 = ((const unsigned*)omc)[(size_t)(pix0+px)*168 + gp];
    float ox = bflo(off2), oy = bfhi(off2);
    float gx = 1.0f + (float)(w0+px) + pts[p/3] + ox;
    float gy = 1.0f + (float)h + pts[p%3] + oy;
    float x0f = floorf(gx), y0f = floorf(gy);
    float wx1 = gx - x0f, wy1 = gy - y0f;
    float wx0 = 1.f-wx1, wy0 = 1.f-wy1;
    int x0 = (int)x0f, y0 = (int)y0f;
    bool xv0 = (x0   >= 1) && (x0   <= 64);
    bool xv1 = (x0+1 >= 1) && (x0+1 <= 64);
    bool yv0 = (y0   >= 1) && (y0   <= 64);
    bool yv1 = (y0+1 >= 1) && (y0+1 <= 64);
    int base = n*HH*WW*C;
    int4 a4;
    a4.x = (yv0&&xv0) ? (base + ((y0-1)*WW + (x0-1))*C)*2 : 0;
    a4.y = (yv0&&xv1) ? (base + ((y0-1)*WW + (x0  ))*C)*2 : 0;
    a4.z = (yv1&&xv0) ? (base + ((y0  )*WW + (x0-1))*C)*2 : 0;
    a4.w = (yv1&&xv1) ? (base + ((y0  )*WW + (x0  ))*C)*2 : 0;
    ((int4*)addrs)[i] = a4;
    ushort4 w4;
    w4.x = to_bf16((yv0&&xv0) ? wx0*wy0 : 0.f);
    w4.y = to_bf16((yv0&&xv1) ? wx1*wy0 : 0.f);
    w4.z = to_bf16((yv1&&xv0) ? wx0*wy1 : 0.f);
    w4.w = to_bf16((yv1&&xv1) ? wx1*wy1 : 0.f);
    ((ushort4*)wts16)[i] = w4;
  }
  __syncthreads();
  if (tid < SPX*12) {
    int px = tid / 12, gg = tid % 12;
    const ushort* mrow = &omc[(size_t)(pix0+px)*336 + 216 + gg*9];
    float lv[P];
    #pragma unroll
    for (int p=0;p<P;p++) lv[p] = bf2f(mrow[p]);
    float m = -1e30f;
    #pragma unroll
    for (int p=0;p<P;p++) m = fmaxf(m, lv[p]);
    float s = 0.f;
    #pragma unroll
    for (int p=0;p<P;p++){ lv[p] = expf(lv[p]-m); s += lv[p]; }
    float cf = 1.0f/(1.0f+expf(-bf2f(omc[(size_t)(pix0+px)*336 + 324 + gg])));
    cfss[px][gg] = cf;
    float onem = (1.0f - cf) / s;
    #pragma unroll
    for (int p=0;p<P;p++) {
      int i = px*108 + gg*9 + p;
      float mp = lv[p]*onem;
      ushort4 w4 = ((const ushort4*)wts16)[i];
      w4.x = to_bf16(bf2f(w4.x)*mp);
      w4.y = to_bf16(bf2f(w4.y)*mp);
      w4.z = to_bf16(bf2f(w4.z)*mp);
      w4.w = to_bf16(bf2f(w4.w)*mp);
      ((ushort4*)wts16)[i] = w4;
    }
  }
  __syncthreads();
  int px = tid / 24, s = tid - (tid/24)*24;
  int g = s >> 1;
  int cb = s * 16;
  const char* xb = (const char*)x_proj;
  float acc[8] = {0.f,0.f,0.f,0.f,0.f,0.f,0.f,0.f};
  #pragma unroll
  for (int pb = 0; pb < 3; pb++) {
    int gp = g*9 + pb*3;
    int4 a0 = ((const int4*)addrs)[px*108+gp];
    int4 a1 = ((const int4*)addrs)[px*108+gp+1];
    int4 a2 = ((const int4*)addrs)[px*108+gp+2];
    ushort4 u0 = ((const ushort4*)wts16)[px*108+gp];
    ushort4 u1 = ((const ushort4*)wts16)[px*108+gp+1];
    ushort4 u2 = ((const ushort4*)wts16)[px*108+gp+2];
    uint4 t00 = *(const uint4*)(xb + (unsigned)(a0.x + cb));
    uint4 t01 = *(const uint4*)(xb + (unsigned)(a0.y + cb));
    uint4 t02 = *(const uint4*)(xb + (unsigned)(a0.z + cb));
    uint4 t03 = *(const uint4*)(xb + (unsigned)(a0.w + cb));
    uint4 t10 = *(const uint4*)(xb + (unsigned)(a1.x + cb));
    uint4 t11 = *(const uint4*)(xb + (unsigned)(a1.y + cb));
    uint4 t12 = *(const uint4*)(xb + (unsigned)(a1.z + cb));
    uint4 t13 = *(const uint4*)(xb + (unsigned)(a1.w + cb));
    uint4 t20 = *(const uint4*)(xb + (unsigned)(a2.x + cb));
    uint4 t21 = *(const uint4*)(xb + (unsigned)(a2.y + cb));
    uint4 t22 = *(const uint4*)(xb + (unsigned)(a2.z + cb));
    uint4 t23 = *(const uint4*)(xb + (unsigned)(a2.w + cb));
    fma8(acc, bf2f(u0.x), t00); fma8(acc, bf2f(u0.y), t01);
    fma8(acc, bf2f(u0.z), t02); fma8(acc, bf2f(u0.w), t03);
    fma8(acc, bf2f(u1.x), t10); fma8(acc, bf2f(u1.y), t11);
    fma8(acc, bf2f(u1.z), t12); fma8(acc, bf2f(u1.w), t13);
    fma8(acc, bf2f(u2.x), t20); fma8(acc, bf2f(u2.y), t21);
    fma8(acc, bf2f(u2.z), t22); fma8(acc, bf2f(u2.w), t23);
  }
  float cf = cfss[px][g];
  uint4 qx = *(const uint4*)(xb + ((size_t)(pix0+px)*C)*2 + cb);
  fma8(acc, cf, qx);
  short8 r;
  #pragma unroll
  for (int k=0;k<8;k++) r[k] = to_bf16(acc[k]);
  *(short8*)&y_out[(size_t)(pix0+px)*C + s*8] = r;
}

// ---------------- patch attention, LDS-tiled 8x8 px/block ----------------
__global__ __launch_bounds__(256) void pattn_kernel(const float* __restrict__ x,
    const ushort* __restrict__ x1, float* __restrict__ out) {
  __shared__ unsigned xs[100*97];      // 38800 B
  __shared__ float psc[64][36];        // 9216 B
  __shared__ float sd_s[64];
  int blk = blockIdx.x;
  int n = blk >> 6;
  int ty = (blk >> 3) & 7, tx = blk & 7;
  int th0 = ty*8, tw0 = tx*8;
  int tid = threadIdx.x;
  const unsigned* x1u = (const unsigned*)x1;
  for (int i = tid; i < 100*96; i += 256) {
    int cell = i / 96, wd = i - cell*96;
    int gy = th0 - 1 + cell/10, gx = tw0 - 1 + cell%10;
    unsigned v = 0;
    if (gy>=0 && gy<HH && gx>=0 && gx<WW)
      v = x1u[(((size_t)n*HH+gy)*WW+gx)*96 + wd];
    xs[cell*97 + wd] = v;
  }
  __syncthreads();
  {
    int px = tid >> 2, qq = tid & 3;
    int py = px >> 3, pxx = px & 7;
    int cell = (py+1)*10 + (pxx+1);
    float cen[48];
    #pragma unroll
    for (int k=0;k<24;k++) {
      unsigned w = xs[cell*97 + qq*24 + k];
      cen[2*k] = bflo(w); cen[2*k+1] = bfhi(w);
    }
    #pragma unroll
    for (int ni=0;ni<9;ni++) {
      int nc = cell + (ni/3-1)*10 + (ni%3-1);
      float a = 0.f;
      #pragma unroll
      for (int k=0;k<24;k++) {
        unsigned w = xs[nc*97 + qq*24 + k];
        a += cen[2*k]*bflo(w) + cen[2*k+1]*bfhi(w);
      }
      psc[px][qq*9+ni] = a;
    }
  }
  __syncthreads();
  if (tid < 64) {
    float sc[9];
    #pragma unroll
    for (int k=0;k<9;k++)
      sc[k] = psc[tid][k] + psc[tid][9+k] + psc[tid][18+k] + psc[tid][27+k];
    float m = sc[0];
    #pragma unroll
    for (int k=1;k<9;k++) m = fmaxf(m, sc[k]);
    float pr[9]; float s = 0.f;
    #pragma unroll
    for (int k=0;k<9;k++){ pr[k] = expf(sc[k]-m); s += pr[k]; }
    float inv = 1.0f/s;
    float mean = 0.f;
    #pragma unroll
    for (int k=0;k<9;k++){ pr[k] *= inv; mean += pr[k]; }
    mean *= (1.0f/9.0f);
    float var = 0.f;
    #pragma unroll
    for (int k=0;k<9;k++){ float d = pr[k]-mean; var += d*d; }
    sd_s[tid] = sqrtf(var*(1.0f/8.0f));
  }
  __syncthreads();
  for (int i = tid; i < 64*96; i += 256) {
    int p2 = i / 96, wd = i - p2*96;
    int py2 = p2 >> 3, px2 = p2 & 7;
    unsigned v = xs[((py2+1)*10 + (px2+1))*97 + wd];
    size_t pix = ((size_t)n*HH + th0+py2)*WW + tw0+px2;
    float2 xv = ((const float2*)x)[pix*96 + wd];
    float sd = sd_s[p2];
    float2 o; o.x = xv.x + bflo(v)*sd; o.y = xv.y + bfhi(v)*sd;
    ((float2*)out)[pix*96 + wd] = o;
  }
}

extern "C" void kernel_launch(void* const* d_in, const int* in_sizes, int n_in,
                              void* d_out, int out_size, void* d_ws, size_t ws_size,
                              hipStream_t stream) {
  const float* x     = (const float*)d_in[0];
  const float* dw_w  = (const float*)d_in[1];
  const float* dw_b  = (const float*)d_in[2];
  const float* ln_g  = (const float*)d_in[3];
  const float* ln_b  = (const float*)d_in[4];
  const float* off_w = (const float*)d_in[5];
  const float* off_b = (const float*)d_in[6];
  const float* msk_w = (const float*)d_in[7];
  const float* msk_b = (const float*)d_in[8];
  const float* in_w  = (const float*)d_in[9];
  const float* in_b  = (const float*)d_in[10];
  const float* out_w = (const float*)d_in[11];
  const float* out_b = (const float*)d_in[12];
  const float* cfs_w = (const float*)d_in[13];
  const float* cfs_b = (const float*)d_in[14];
  float* outp = (float*)d_out;

  ushort* omc    = (ushort*)d_ws;                        // NPIX*336 bf16
  ushort* xproj  = omc + (size_t)NPIX*336;               // NPIX*192 bf16
  ushort* x1_bf  = xproj + (size_t)NPIX*192;             // NPIX*192 bf16
  ushort* u_bf   = x1_bf + (size_t)NPIX*192;             // NPIX*192 bf16 (u, then y2)
  ushort* in_wt  = u_bf + (size_t)NPIX*192;              // 192*192
  ushort* out_wt = in_wt + 192*192;                      // 192*192
  ushort* wf_t   = out_wt + 192*192;                     // 384*192
  float*  bfb    = (float*)(wf_t + 384*192);             // 384 f32

  prep_w_kernel<<<(147456+255)/256, 256, 0, stream>>>(in_w, out_w, off_w, msk_w, cfs_w,
                                                       off_b, msk_b, cfs_b,
                                                       in_wt, out_wt, wf_t, bfb);
  // x_proj (bf16) = x @ in_w + in_b  (f32 A converted in-register)
  mfma_gemm<192,192,true,true><<<dim3(NPIX/64, 3), 256, 0, stream>>>(x, in_wt, in_b, xproj);
  // u (bf16) = GELU(LN(dwconv(x)))  (XCD-swizzled)
  dw_ln_gelu_kernel<<<NB*HH*4, 192, 0, stream>>>(x, dw_w, dw_b, ln_g, ln_b, u_bf);
  // omc (bf16) = u @ wf + bf
  mfma_gemm<384,336,true,false><<<dim3(NPIX/64, 6), 256, 0, stream>>>(u_bf, wf_t, bfb, omc);
  // y2 (bf16) = dcn-sample + gated blend (overwrites u)
  sample_kernel<<<NPIX/SPX, 192, 0, stream>>>(omc, xproj, u_bf);
  // x1 (bf16) = y2 @ out_w + out_b
  mfma_gemm<192,192,true,false><<<dim3(NPIX/64, 3), 256, 0, stream>>>(u_bf, out_wt, out_b, x1_bf);
  // out = x + x1 * patch_std
  pattn_kernel<<<NB*64, 256, 0, stream>>>(x, x1_bf, outp);
}